// Round 1
// baseline (2695.490 us; speedup 1.0000x reference)
//
#include <hip/hip_runtime.h>

// out = sigmoid(alpha)[:,None] * 0.5 * (ax - x) + x0
// ax = segment_sum(adj_values[:,None] * x[adj_col], adj_row)
//
// Strategy: fold the per-destination-row scale sig(alpha[row])*0.5 into each
// edge's coefficient, initialize out = x0 - 0.5*sig(alpha)*x, then scatter
// atomicAdd coef*x[col] into out[row]. One kernel pair, no ax buffer.

#define DIM 128
#define VEC 4            // float4 per thread
#define CHUNKS (DIM / (VEC))   // 32 chunks of 4 floats per row

__device__ __forceinline__ float sigmoidf_(float a) {
    return 1.0f / (1.0f + __expf(-a));
}

// out[i,:] = x0[i,:] - 0.5*sig(alpha[i]) * x[i,:]
__global__ void init_out_kernel(const float* __restrict__ x,
                                const float* __restrict__ x0,
                                const float* __restrict__ alpha,
                                float* __restrict__ out,
                                int n_nodes) {
    int i = blockIdx.x * blockDim.x + threadIdx.x;   // over n_nodes * CHUNKS
    int total = n_nodes * CHUNKS;
    if (i >= total) return;
    int node = i >> 5;               // i / CHUNKS
    float s = 0.5f * sigmoidf_(alpha[node]);
    float4 xv  = reinterpret_cast<const float4*>(x)[i];
    float4 x0v = reinterpret_cast<const float4*>(x0)[i];
    float4 o;
    o.x = x0v.x - s * xv.x;
    o.y = x0v.y - s * xv.y;
    o.z = x0v.z - s * xv.z;
    o.w = x0v.w - s * xv.w;
    reinterpret_cast<float4*>(out)[i] = o;
}

// per (edge, chunk): out[row, c*4 .. c*4+3] += coef * x[col, c*4 .. c*4+3]
// coef = 0.5 * sig(alpha[row]) * vals[e]
__global__ void spmm_scatter_kernel(const float* __restrict__ x,
                                    const float* __restrict__ alpha,
                                    const float* __restrict__ vals,
                                    const int* __restrict__ row,
                                    const int* __restrict__ col,
                                    float* __restrict__ out,
                                    int n_edges) {
    long long gid = (long long)blockIdx.x * blockDim.x + threadIdx.x;
    long long total = (long long)n_edges * CHUNKS;
    if (gid >= total) return;
    int e = (int)(gid >> 5);         // gid / CHUNKS
    int c = (int)(gid & (CHUNKS - 1));
    int r  = row[e];
    int cl = col[e];
    float coef = 0.5f * vals[e] * sigmoidf_(alpha[r]);
    float4 xv = reinterpret_cast<const float4*>(x + (long long)cl * DIM)[c];
    float* dst = out + (long long)r * DIM + c * VEC;
    atomicAdd(dst + 0, coef * xv.x);
    atomicAdd(dst + 1, coef * xv.y);
    atomicAdd(dst + 2, coef * xv.z);
    atomicAdd(dst + 3, coef * xv.w);
}

extern "C" void kernel_launch(void* const* d_in, const int* in_sizes, int n_in,
                              void* d_out, int out_size, void* d_ws, size_t ws_size,
                              hipStream_t stream) {
    // inputs: 0=t(unused), 1=x[N,D], 2=x0[N,D], 3=alpha[N], 4=vals[E],
    //         5=row[E](i32), 6=col[E](i32)
    const float* x     = (const float*)d_in[1];
    const float* x0    = (const float*)d_in[2];
    const float* alpha = (const float*)d_in[3];
    const float* vals  = (const float*)d_in[4];
    const int*   row   = (const int*)d_in[5];
    const int*   col   = (const int*)d_in[6];
    float* out = (float*)d_out;

    int n_nodes = in_sizes[3];
    int n_edges = in_sizes[4];

    {
        int total = n_nodes * CHUNKS;
        int block = 256;
        int grid = (total + block - 1) / block;
        init_out_kernel<<<grid, block, 0, stream>>>(x, x0, alpha, out, n_nodes);
    }
    {
        long long total = (long long)n_edges * CHUNKS;
        int block = 256;
        long long grid = (total + block - 1) / block;
        spmm_scatter_kernel<<<(int)grid, block, 0, stream>>>(
            x, alpha, vals, row, col, out, n_edges);
    }
}

// Round 2
// 595.135 us; speedup vs baseline: 4.5292x; 4.5292x over previous
//
#include <hip/hip_runtime.h>

// out = sigmoid(alpha)[:,None] * 0.5 * (ax - x) + x0
// ax = segment_sum(adj_values[:,None] * x[adj_col], adj_row)
//
// R2 strategy: kill the 204.8M float atomics (R1 bottleneck: WRITE_SIZE 3.2GB,
// atomic-pipe-bound at 17% HBM). Build CSR-by-destination in workspace every
// call (histogram -> single-block scan -> permute), then one wave (64 lanes)
// per destination row gathers & accumulates in registers, fused with the
// x0 - s*x term, and does ONE non-atomic 512B store per row.

#define DIM 128
#define SCAN_THREADS 1024

__device__ __forceinline__ float sigmoidf_(float a) {
    return 1.0f / (1.0f + __expf(-a));
}

// counts[row[e]]++ over all edges
__global__ void hist_kernel(const int* __restrict__ row, int* __restrict__ counts,
                            int n_edges) {
    for (int i = blockIdx.x * blockDim.x + threadIdx.x; i < n_edges;
         i += gridDim.x * blockDim.x) {
        atomicAdd(&counts[row[i]], 1);
    }
}

// exclusive scan of counts[0..n) -> offsets[0..n], cursor = offsets copy
__global__ void scan_kernel(const int* __restrict__ counts,
                            int* __restrict__ offsets,
                            int* __restrict__ cursor, int n) {
    __shared__ int ssum[SCAN_THREADS];
    int t = threadIdx.x;
    int per = (n + SCAN_THREADS - 1) / SCAN_THREADS;
    int start = t * per;
    int end = start + per; if (end > n) end = n;
    int sum = 0;
    for (int i = start; i < end; ++i) sum += counts[i];
    ssum[t] = sum;
    __syncthreads();
    // Hillis-Steele inclusive scan over thread sums
    for (int off = 1; off < SCAN_THREADS; off <<= 1) {
        int v = (t >= off) ? ssum[t - off] : 0;
        __syncthreads();
        ssum[t] += v;
        __syncthreads();
    }
    int run = (t == 0) ? 0 : ssum[t - 1];
    for (int i = start; i < end; ++i) {
        offsets[i] = run;
        cursor[i] = run;
        run += counts[i];
    }
    if (t == SCAN_THREADS - 1) offsets[n] = run;
}

// permute edges into destination-sorted order
__global__ void permute_kernel(const int* __restrict__ row,
                               const int* __restrict__ col,
                               const float* __restrict__ vals,
                               int* __restrict__ cursor,
                               int* __restrict__ scol,
                               float* __restrict__ sval, int n_edges) {
    for (int i = blockIdx.x * blockDim.x + threadIdx.x; i < n_edges;
         i += gridDim.x * blockDim.x) {
        int r = row[i];
        int p = atomicAdd(&cursor[r], 1);
        scol[p] = col[i];
        sval[p] = vals[i];
    }
}

// one 64-lane wave per destination row; lane owns 2 columns (float2).
// out[r] = x0[r] - s*x[r] + s * sum_e val[e]*x[col[e]],  s = 0.5*sig(alpha[r])
__global__ __launch_bounds__(256)
void csr_gather_kernel(const float* __restrict__ x,
                       const float* __restrict__ x0,
                       const float* __restrict__ alpha,
                       const int* __restrict__ offsets,
                       const int* __restrict__ scol,
                       const float* __restrict__ sval,
                       float* __restrict__ out, int n_nodes) {
    int gid = blockIdx.x * blockDim.x + threadIdx.x;
    int r = gid >> 6;           // wave (64 lanes) per row
    int lane = gid & 63;        // lane owns float2 -> 128 floats/row
    if (r >= n_nodes) return;
    float s = 0.5f * sigmoidf_(alpha[r]);
    size_t rowbase = (size_t)r * DIM;
    float2 xv = reinterpret_cast<const float2*>(x + rowbase)[lane];
    float2 acc = reinterpret_cast<const float2*>(x0 + rowbase)[lane];
    acc.x -= s * xv.x;
    acc.y -= s * xv.y;
    int beg = offsets[r], stop = offsets[r + 1];
    for (int p = beg; p < stop; ++p) {
        int c = scol[p];                      // broadcast load
        float coef = s * sval[p];             // broadcast load
        float2 v = reinterpret_cast<const float2*>(x + (size_t)c * DIM)[lane];
        acc.x += coef * v.x;
        acc.y += coef * v.y;
    }
    reinterpret_cast<float2*>(out + rowbase)[lane] = acc;
}

extern "C" void kernel_launch(void* const* d_in, const int* in_sizes, int n_in,
                              void* d_out, int out_size, void* d_ws, size_t ws_size,
                              hipStream_t stream) {
    // inputs: 0=t(unused), 1=x[N,D], 2=x0[N,D], 3=alpha[N], 4=vals[E],
    //         5=row[E](i32), 6=col[E](i32)
    const float* x     = (const float*)d_in[1];
    const float* x0    = (const float*)d_in[2];
    const float* alpha = (const float*)d_in[3];
    const float* vals  = (const float*)d_in[4];
    const int*   row   = (const int*)d_in[5];
    const int*   col   = (const int*)d_in[6];
    float* out = (float*)d_out;

    int n_nodes = in_sizes[3];
    int n_edges = in_sizes[4];

    // workspace layout (16B-aligned chunks)
    size_t np1 = (size_t)((n_nodes + 1 + 3) & ~3);
    int*   counts  = (int*)d_ws;
    int*   offsets = counts + np1;
    int*   cursor  = offsets + np1;
    int*   scol    = cursor + np1;
    float* sval    = (float*)(scol + ((n_edges + 3) & ~3));
    // total: 3*np1*4 + 2*E*4 ~= 14 MB; assumed <= ws_size

    hipMemsetAsync(counts, 0, np1 * sizeof(int), stream);

    {
        int block = 256;
        int grid = (n_edges + block - 1) / block;
        if (grid > 4096) grid = 4096;
        hist_kernel<<<grid, block, 0, stream>>>(row, counts, n_edges);
    }
    scan_kernel<<<1, SCAN_THREADS, 0, stream>>>(counts, offsets, cursor, n_nodes);
    {
        int block = 256;
        int grid = (n_edges + block - 1) / block;
        if (grid > 4096) grid = 4096;
        permute_kernel<<<grid, block, 0, stream>>>(row, col, vals, cursor,
                                                   scol, sval, n_edges);
    }
    {
        long long total = (long long)n_nodes * 64;
        int block = 256;
        int grid = (int)((total + block - 1) / block);
        csr_gather_kernel<<<grid, block, 0, stream>>>(x, x0, alpha, offsets,
                                                      scol, sval, out, n_nodes);
    }
}

// Round 3
// 379.910 us; speedup vs baseline: 7.0951x; 1.5665x over previous
//
#include <hip/hip_runtime.h>

// out = sigmoid(alpha)[:,None] * 0.5 * (ax - x) + x0
// ax = segment_sum(adj_values[:,None] * x[adj_col], adj_row)
//
// R3: R2's single-block scan was 230us (latency-bound, one CU). Replace with
// hierarchical scan (partial -> blocksums -> add-base). Pack (col,val) into
// int2 for the permute scatter (one 8B store per edge instead of two 4B).

#define DIM 128
#define TILE 1024            // elements per scan block (256 thr x int4)

__device__ __forceinline__ float sigmoidf_(float a) {
    return 1.0f / (1.0f + __expf(-a));
}

// counts[row[e]]++ over all edges
__global__ void hist_kernel(const int* __restrict__ row, int* __restrict__ counts,
                            int n_edges) {
    for (int i = blockIdx.x * blockDim.x + threadIdx.x; i < n_edges;
         i += gridDim.x * blockDim.x) {
        atomicAdd(&counts[row[i]], 1);
    }
}

// per-block exclusive scan over TILE elements; write partial offsets + block sum
__global__ __launch_bounds__(256)
void scan_partial_kernel(const int* __restrict__ counts,
                         int* __restrict__ partial,
                         int* __restrict__ blocksums, int n) {
    __shared__ int ts[256];
    int t = threadIdx.x;
    int base = blockIdx.x * TILE + t * 4;
    int4 v = make_int4(0, 0, 0, 0);
    if (base + 3 < n) {
        v = *reinterpret_cast<const int4*>(counts + base);
    } else {
        if (base + 0 < n) v.x = counts[base + 0];
        if (base + 1 < n) v.y = counts[base + 1];
        if (base + 2 < n) v.z = counts[base + 2];
        if (base + 3 < n) v.w = counts[base + 3];
    }
    int s0 = v.x, s1 = s0 + v.y, s2 = s1 + v.z, s3 = s2 + v.w;
    ts[t] = s3;
    __syncthreads();
    for (int off = 1; off < 256; off <<= 1) {
        int u = (t >= off) ? ts[t - off] : 0;
        __syncthreads();
        ts[t] += u;
        __syncthreads();
    }
    int texcl = (t == 0) ? 0 : ts[t - 1];
    if (t == 255) blocksums[blockIdx.x] = ts[255];
    int4 o;
    o.x = texcl;
    o.y = texcl + s0;
    o.z = texcl + s1;
    o.w = texcl + s2;
    if (base + 3 < n) {
        *reinterpret_cast<int4*>(partial + base) = o;
    } else {
        if (base + 0 < n) partial[base + 0] = o.x;
        if (base + 1 < n) partial[base + 1] = o.y;
        if (base + 2 < n) partial[base + 2] = o.z;
        if (base + 3 < n) partial[base + 3] = o.w;
    }
}

// exclusive scan of blocksums[0..nb) in place (nb <= 1024)
__global__ __launch_bounds__(1024)
void scan_blocksums_kernel(int* __restrict__ blocksums, int nb) {
    __shared__ int ts[1024];
    int t = threadIdx.x;
    ts[t] = (t < nb) ? blocksums[t] : 0;
    __syncthreads();
    for (int off = 1; off < 1024; off <<= 1) {
        int u = (t >= off) ? ts[t - off] : 0;
        __syncthreads();
        ts[t] += u;
        __syncthreads();
    }
    if (t < nb) blocksums[t] = (t == 0) ? 0 : ts[t - 1];
}

// offsets = partial + blockbase; cursor = offsets
__global__ __launch_bounds__(256)
void add_base_kernel(int* __restrict__ offsets,
                     int* __restrict__ cursor,
                     const int* __restrict__ blocksums, int n) {
    int bb = blocksums[blockIdx.x];
    int base = blockIdx.x * TILE + threadIdx.x * 4;
    if (base + 3 < n) {
        int4 v = *reinterpret_cast<const int4*>(offsets + base);
        v.x += bb; v.y += bb; v.z += bb; v.w += bb;
        *reinterpret_cast<int4*>(offsets + base) = v;
        *reinterpret_cast<int4*>(cursor + base) = v;
    } else {
        for (int k = 0; k < 4; ++k) {
            if (base + k < n) {
                int v = offsets[base + k] + bb;
                offsets[base + k] = v;
                cursor[base + k] = v;
            }
        }
    }
}

// permute edges into destination-sorted order; pack (col, val) into int2
__global__ void permute_kernel(const int* __restrict__ row,
                               const int* __restrict__ col,
                               const float* __restrict__ vals,
                               int* __restrict__ cursor,
                               int2* __restrict__ epack, int n_edges) {
    for (int i = blockIdx.x * blockDim.x + threadIdx.x; i < n_edges;
         i += gridDim.x * blockDim.x) {
        int r = row[i];
        int p = atomicAdd(&cursor[r], 1);
        epack[p] = make_int2(col[i], __float_as_int(vals[i]));
    }
}

// one 64-lane wave per destination row; lane owns 2 columns (float2).
// out[r] = x0[r] - s*x[r] + s * sum_e val[e]*x[col[e]],  s = 0.5*sig(alpha[r])
__global__ __launch_bounds__(256)
void csr_gather_kernel(const float* __restrict__ x,
                       const float* __restrict__ x0,
                       const float* __restrict__ alpha,
                       const int* __restrict__ offsets,
                       const int2* __restrict__ epack,
                       float* __restrict__ out, int n_nodes, int n_edges) {
    int gid = blockIdx.x * blockDim.x + threadIdx.x;
    int r = gid >> 6;           // wave (64 lanes) per row
    int lane = gid & 63;        // lane owns float2 -> 128 floats/row
    if (r >= n_nodes) return;
    float s = 0.5f * sigmoidf_(alpha[r]);
    size_t rowbase = (size_t)r * DIM;
    float2 xv = reinterpret_cast<const float2*>(x + rowbase)[lane];
    float2 acc = reinterpret_cast<const float2*>(x0 + rowbase)[lane];
    acc.x -= s * xv.x;
    acc.y -= s * xv.y;
    int beg = offsets[r];
    int stop = (r + 1 < n_nodes) ? offsets[r + 1] : n_edges;
    for (int p = beg; p < stop; ++p) {
        int2 e = epack[p];                    // broadcast load
        float coef = s * __int_as_float(e.y);
        float2 v = reinterpret_cast<const float2*>(x + (size_t)e.x * DIM)[lane];
        acc.x += coef * v.x;
        acc.y += coef * v.y;
    }
    reinterpret_cast<float2*>(out + rowbase)[lane] = acc;
}

extern "C" void kernel_launch(void* const* d_in, const int* in_sizes, int n_in,
                              void* d_out, int out_size, void* d_ws, size_t ws_size,
                              hipStream_t stream) {
    // inputs: 0=t(unused), 1=x[N,D], 2=x0[N,D], 3=alpha[N], 4=vals[E],
    //         5=row[E](i32), 6=col[E](i32)
    const float* x     = (const float*)d_in[1];
    const float* x0    = (const float*)d_in[2];
    const float* alpha = (const float*)d_in[3];
    const float* vals  = (const float*)d_in[4];
    const int*   row   = (const int*)d_in[5];
    const int*   col   = (const int*)d_in[6];
    float* out = (float*)d_out;

    int n_nodes = in_sizes[3];
    int n_edges = in_sizes[4];
    int nblocks = (n_nodes + TILE - 1) / TILE;   // scan blocks (98 for 100k)

    // workspace layout (16B-aligned chunks)
    size_t npad = (size_t)((n_nodes + 3) & ~3);
    int*  counts    = (int*)d_ws;
    int*  offsets   = counts + npad;
    int*  cursor    = offsets + npad;
    int*  blocksums = cursor + npad;
    int2* epack     = (int2*)(blocksums + 1024);
    // total ~= 3*400KB + 4KB + 12.8MB ~= 14 MB

    hipMemsetAsync(counts, 0, npad * sizeof(int), stream);

    {
        int block = 256;
        int grid = (n_edges + block - 1) / block;
        if (grid > 4096) grid = 4096;
        hist_kernel<<<grid, block, 0, stream>>>(row, counts, n_edges);
    }
    scan_partial_kernel<<<nblocks, 256, 0, stream>>>(counts, offsets,
                                                     blocksums, n_nodes);
    scan_blocksums_kernel<<<1, 1024, 0, stream>>>(blocksums, nblocks);
    add_base_kernel<<<nblocks, 256, 0, stream>>>(offsets, cursor, blocksums,
                                                 n_nodes);
    {
        int block = 256;
        int grid = (n_edges + block - 1) / block;
        if (grid > 4096) grid = 4096;
        permute_kernel<<<grid, block, 0, stream>>>(row, col, vals, cursor,
                                                   epack, n_edges);
    }
    {
        long long total = (long long)n_nodes * 64;
        int block = 256;
        int grid = (int)((total + block - 1) / block);
        csr_gather_kernel<<<grid, block, 0, stream>>>(x, x0, alpha, offsets,
                                                      epack, out, n_nodes,
                                                      n_edges);
    }
}

// Round 4
// 337.398 us; speedup vs baseline: 7.9891x; 1.1260x over previous
//
#include <hip/hip_runtime.h>

// out = sigmoid(alpha)[:,None] * 0.5 * (ax - x) + x0
// ax = segment_sum(adj_values[:,None] * x[adj_col], adj_row)
//
// R4: gather kernel is cache-state-invariant at ~200us (not HBM-bound).
// Hypothesis: per-edge epack-load -> address dependency serializes ~2 memory
// latencies per edge (VGPR_Count=12, no pipelining). Fix: lane-parallel epack
// load (64 edges in one vector load) + __shfl broadcast for addresses, with
// manual 4-wide gather batching. Also int4-vectorize hist/permute.

#define DIM 128
#define TILE 1024            // elements per scan block (256 thr x int4)

__device__ __forceinline__ float sigmoidf_(float a) {
    return 1.0f / (1.0f + __expf(-a));
}

// counts[row[e]]++ over all edges, 4 edges per thread
__global__ void hist_kernel(const int* __restrict__ row, int* __restrict__ counts,
                            int n_edges) {
    int n4 = n_edges >> 2;
    for (int i = blockIdx.x * blockDim.x + threadIdx.x; i < n4;
         i += gridDim.x * blockDim.x) {
        int4 r = reinterpret_cast<const int4*>(row)[i];
        atomicAdd(&counts[r.x], 1);
        atomicAdd(&counts[r.y], 1);
        atomicAdd(&counts[r.z], 1);
        atomicAdd(&counts[r.w], 1);
    }
    if (blockIdx.x == 0 && threadIdx.x == 0) {
        for (int i = n4 << 2; i < n_edges; ++i) atomicAdd(&counts[row[i]], 1);
    }
}

// per-block exclusive scan over TILE elements; write partial offsets + block sum
__global__ __launch_bounds__(256)
void scan_partial_kernel(const int* __restrict__ counts,
                         int* __restrict__ partial,
                         int* __restrict__ blocksums, int n) {
    __shared__ int ts[256];
    int t = threadIdx.x;
    int base = blockIdx.x * TILE + t * 4;
    int4 v = make_int4(0, 0, 0, 0);
    if (base + 3 < n) {
        v = *reinterpret_cast<const int4*>(counts + base);
    } else {
        if (base + 0 < n) v.x = counts[base + 0];
        if (base + 1 < n) v.y = counts[base + 1];
        if (base + 2 < n) v.z = counts[base + 2];
        if (base + 3 < n) v.w = counts[base + 3];
    }
    int s0 = v.x, s1 = s0 + v.y, s2 = s1 + v.z, s3 = s2 + v.w;
    ts[t] = s3;
    __syncthreads();
    for (int off = 1; off < 256; off <<= 1) {
        int u = (t >= off) ? ts[t - off] : 0;
        __syncthreads();
        ts[t] += u;
        __syncthreads();
    }
    int texcl = (t == 0) ? 0 : ts[t - 1];
    if (t == 255) blocksums[blockIdx.x] = ts[255];
    int4 o;
    o.x = texcl;
    o.y = texcl + s0;
    o.z = texcl + s1;
    o.w = texcl + s2;
    if (base + 3 < n) {
        *reinterpret_cast<int4*>(partial + base) = o;
    } else {
        if (base + 0 < n) partial[base + 0] = o.x;
        if (base + 1 < n) partial[base + 1] = o.y;
        if (base + 2 < n) partial[base + 2] = o.z;
        if (base + 3 < n) partial[base + 3] = o.w;
    }
}

// exclusive scan of blocksums[0..nb) in place (nb <= 1024)
__global__ __launch_bounds__(1024)
void scan_blocksums_kernel(int* __restrict__ blocksums, int nb) {
    __shared__ int ts[1024];
    int t = threadIdx.x;
    ts[t] = (t < nb) ? blocksums[t] : 0;
    __syncthreads();
    for (int off = 1; off < 1024; off <<= 1) {
        int u = (t >= off) ? ts[t - off] : 0;
        __syncthreads();
        ts[t] += u;
        __syncthreads();
    }
    if (t < nb) blocksums[t] = (t == 0) ? 0 : ts[t - 1];
}

// offsets = partial + blockbase; cursor = offsets
__global__ __launch_bounds__(256)
void add_base_kernel(int* __restrict__ offsets,
                     int* __restrict__ cursor,
                     const int* __restrict__ blocksums, int n) {
    int bb = blocksums[blockIdx.x];
    int base = blockIdx.x * TILE + threadIdx.x * 4;
    if (base + 3 < n) {
        int4 v = *reinterpret_cast<const int4*>(offsets + base);
        v.x += bb; v.y += bb; v.z += bb; v.w += bb;
        *reinterpret_cast<int4*>(offsets + base) = v;
        *reinterpret_cast<int4*>(cursor + base) = v;
    } else {
        for (int k = 0; k < 4; ++k) {
            if (base + k < n) {
                int v = offsets[base + k] + bb;
                offsets[base + k] = v;
                cursor[base + k] = v;
            }
        }
    }
}

// permute edges into destination-sorted order; pack (col, val) into int2.
// 4 edges per thread via int4/float4 loads.
__global__ void permute_kernel(const int* __restrict__ row,
                               const int* __restrict__ col,
                               const float* __restrict__ vals,
                               int* __restrict__ cursor,
                               int2* __restrict__ epack, int n_edges) {
    int n4 = n_edges >> 2;
    for (int i = blockIdx.x * blockDim.x + threadIdx.x; i < n4;
         i += gridDim.x * blockDim.x) {
        int4   r = reinterpret_cast<const int4*>(row)[i];
        int4   c = reinterpret_cast<const int4*>(col)[i];
        float4 v = reinterpret_cast<const float4*>(vals)[i];
        int p0 = atomicAdd(&cursor[r.x], 1);
        epack[p0] = make_int2(c.x, __float_as_int(v.x));
        int p1 = atomicAdd(&cursor[r.y], 1);
        epack[p1] = make_int2(c.y, __float_as_int(v.y));
        int p2 = atomicAdd(&cursor[r.z], 1);
        epack[p2] = make_int2(c.z, __float_as_int(v.z));
        int p3 = atomicAdd(&cursor[r.w], 1);
        epack[p3] = make_int2(c.w, __float_as_int(v.w));
    }
    if (blockIdx.x == 0 && threadIdx.x == 0) {
        for (int i = n4 << 2; i < n_edges; ++i) {
            int p = atomicAdd(&cursor[row[i]], 1);
            epack[p] = make_int2(col[i], __float_as_int(vals[i]));
        }
    }
}

// one 64-lane wave per destination row; lane owns 2 columns (float2).
// Edge metadata is loaded lane-parallel (one epack entry per lane) and
// broadcast via __shfl, so gather addresses never wait on a memory load.
// Gathers issued 4-wide before accumulation.
__global__ __launch_bounds__(256)
void csr_gather_kernel(const float* __restrict__ x,
                       const float* __restrict__ x0,
                       const float* __restrict__ alpha,
                       const int* __restrict__ offsets,
                       const int2* __restrict__ epack,
                       float* __restrict__ out, int n_nodes, int n_edges) {
    int gid = blockIdx.x * blockDim.x + threadIdx.x;
    int r = gid >> 6;           // wave (64 lanes) per row
    int lane = gid & 63;        // lane owns float2 -> 128 floats/row
    if (r >= n_nodes) return;
    float s = 0.5f * sigmoidf_(alpha[r]);
    const float2* xp = reinterpret_cast<const float2*>(x);
    int rb = r * 64;            // float2 index of row base
    float2 xv = xp[rb + lane];
    float2 acc = reinterpret_cast<const float2*>(x0)[rb + lane];
    acc.x -= s * xv.x;
    acc.y -= s * xv.y;
    int beg = offsets[r];
    int stop = (r + 1 < n_nodes) ? offsets[r + 1] : n_edges;
    for (int chunk = beg; chunk < stop; chunk += 64) {
        int m = stop - chunk;
        if (m > 64) m = 64;
        int2 e = make_int2(0, 0);
        if (lane < m) e = epack[chunk + lane];
        int k = 0;
        for (; k + 4 <= m; k += 4) {
            int c0 = __shfl(e.x, k + 0);
            int c1 = __shfl(e.x, k + 1);
            int c2 = __shfl(e.x, k + 2);
            int c3 = __shfl(e.x, k + 3);
            float w0 = s * __int_as_float(__shfl(e.y, k + 0));
            float w1 = s * __int_as_float(__shfl(e.y, k + 1));
            float w2 = s * __int_as_float(__shfl(e.y, k + 2));
            float w3 = s * __int_as_float(__shfl(e.y, k + 3));
            float2 v0 = xp[(size_t)c0 * 64 + lane];
            float2 v1 = xp[(size_t)c1 * 64 + lane];
            float2 v2 = xp[(size_t)c2 * 64 + lane];
            float2 v3 = xp[(size_t)c3 * 64 + lane];
            acc.x += w0 * v0.x; acc.y += w0 * v0.y;
            acc.x += w1 * v1.x; acc.y += w1 * v1.y;
            acc.x += w2 * v2.x; acc.y += w2 * v2.y;
            acc.x += w3 * v3.x; acc.y += w3 * v3.y;
        }
        for (; k < m; ++k) {
            int c = __shfl(e.x, k);
            float w = s * __int_as_float(__shfl(e.y, k));
            float2 v = xp[(size_t)c * 64 + lane];
            acc.x += w * v.x;
            acc.y += w * v.y;
        }
    }
    reinterpret_cast<float2*>(out)[rb + lane] = acc;
}

extern "C" void kernel_launch(void* const* d_in, const int* in_sizes, int n_in,
                              void* d_out, int out_size, void* d_ws, size_t ws_size,
                              hipStream_t stream) {
    // inputs: 0=t(unused), 1=x[N,D], 2=x0[N,D], 3=alpha[N], 4=vals[E],
    //         5=row[E](i32), 6=col[E](i32)
    const float* x     = (const float*)d_in[1];
    const float* x0    = (const float*)d_in[2];
    const float* alpha = (const float*)d_in[3];
    const float* vals  = (const float*)d_in[4];
    const int*   row   = (const int*)d_in[5];
    const int*   col   = (const int*)d_in[6];
    float* out = (float*)d_out;

    int n_nodes = in_sizes[3];
    int n_edges = in_sizes[4];
    int nblocks = (n_nodes + TILE - 1) / TILE;   // scan blocks (98 for 100k)

    // workspace layout (16B-aligned chunks)
    size_t npad = (size_t)((n_nodes + 3) & ~3);
    int*  counts    = (int*)d_ws;
    int*  offsets   = counts + npad;
    int*  cursor    = offsets + npad;
    int*  blocksums = cursor + npad;
    int2* epack     = (int2*)(blocksums + 1024);
    // total ~= 3*400KB + 4KB + 12.8MB ~= 14 MB

    hipMemsetAsync(counts, 0, npad * sizeof(int), stream);

    {
        int block = 256;
        int grid = ((n_edges >> 2) + block - 1) / block;
        if (grid > 4096) grid = 4096;
        hist_kernel<<<grid, block, 0, stream>>>(row, counts, n_edges);
    }
    scan_partial_kernel<<<nblocks, 256, 0, stream>>>(counts, offsets,
                                                     blocksums, n_nodes);
    scan_blocksums_kernel<<<1, 1024, 0, stream>>>(blocksums, nblocks);
    add_base_kernel<<<nblocks, 256, 0, stream>>>(offsets, cursor, blocksums,
                                                 n_nodes);
    {
        int block = 256;
        int grid = ((n_edges >> 2) + block - 1) / block;
        if (grid > 4096) grid = 4096;
        permute_kernel<<<grid, block, 0, stream>>>(row, col, vals, cursor,
                                                   epack, n_edges);
    }
    {
        long long total = (long long)n_nodes * 64;
        int block = 256;
        int grid = (int)((total + block - 1) / block);
        csr_gather_kernel<<<grid, block, 0, stream>>>(x, x0, alpha, offsets,
                                                      epack, out, n_nodes,
                                                      n_edges);
    }
}

// Round 5
// 242.900 us; speedup vs baseline: 11.0971x; 1.3890x over previous
//
#include <hip/hip_runtime.h>

// out = sigmoid(alpha)[:,None] * 0.5 * (ax - x) + x0
// ax = segment_sum(adj_values[:,None] * x[adj_col], adj_row)
//
// R5: R4's permute did 1.6M random 8B stores -> 101MB of random-64B-line HBM
// writebacks at ~810 GB/s (random-write efficiency ceiling). Replace with a
// two-level counting sort whose global traffic is coalesced:
//   Phase A: bin edges into 128-row buckets via LDS staging (runs of
//            consecutive slots per bucket), write epackA.
//   Phase B: block per bucket: LDS-load region, scatter to CSR order via LDS
//            row cursors, stream out coalesced to epackB.
// Gather (wave/row, shfl-broadcast, 4-wide) unchanged, reads epackB.

#define DIM 128
#define TILE 1024            // elements per scan block (256 thr x int4)
#define RPB 128              // rows per bucket (power of 2)
#define ACHUNK 4096          // edges per phase-A block
#define BCAP 4096            // phase-B LDS capacity (entries)
#define NBMAX 1024           // max buckets supported in phase-A LDS

__device__ __forceinline__ float sigmoidf_(float a) {
    return 1.0f / (1.0f + __expf(-a));
}

// counts[row[e]]++ over all edges, 4 edges per thread
__global__ void hist_kernel(const int* __restrict__ row, int* __restrict__ counts,
                            int n_edges) {
    int n4 = n_edges >> 2;
    for (int i = blockIdx.x * blockDim.x + threadIdx.x; i < n4;
         i += gridDim.x * blockDim.x) {
        int4 r = reinterpret_cast<const int4*>(row)[i];
        atomicAdd(&counts[r.x], 1);
        atomicAdd(&counts[r.y], 1);
        atomicAdd(&counts[r.z], 1);
        atomicAdd(&counts[r.w], 1);
    }
    if (blockIdx.x == 0 && threadIdx.x == 0) {
        for (int i = n4 << 2; i < n_edges; ++i) atomicAdd(&counts[row[i]], 1);
    }
}

// per-block exclusive scan over TILE elements; write partial offsets + block sum
__global__ __launch_bounds__(256)
void scan_partial_kernel(const int* __restrict__ counts,
                         int* __restrict__ partial,
                         int* __restrict__ blocksums, int n) {
    __shared__ int ts[256];
    int t = threadIdx.x;
    int base = blockIdx.x * TILE + t * 4;
    int4 v = make_int4(0, 0, 0, 0);
    if (base + 3 < n) {
        v = *reinterpret_cast<const int4*>(counts + base);
    } else {
        if (base + 0 < n) v.x = counts[base + 0];
        if (base + 1 < n) v.y = counts[base + 1];
        if (base + 2 < n) v.z = counts[base + 2];
        if (base + 3 < n) v.w = counts[base + 3];
    }
    int s0 = v.x, s1 = s0 + v.y, s2 = s1 + v.z, s3 = s2 + v.w;
    ts[t] = s3;
    __syncthreads();
    for (int off = 1; off < 256; off <<= 1) {
        int u = (t >= off) ? ts[t - off] : 0;
        __syncthreads();
        ts[t] += u;
        __syncthreads();
    }
    int texcl = (t == 0) ? 0 : ts[t - 1];
    if (t == 255) blocksums[blockIdx.x] = ts[255];
    int4 o;
    o.x = texcl;
    o.y = texcl + s0;
    o.z = texcl + s1;
    o.w = texcl + s2;
    if (base + 3 < n) {
        *reinterpret_cast<int4*>(partial + base) = o;
    } else {
        if (base + 0 < n) partial[base + 0] = o.x;
        if (base + 1 < n) partial[base + 1] = o.y;
        if (base + 2 < n) partial[base + 2] = o.z;
        if (base + 3 < n) partial[base + 3] = o.w;
    }
}

// exclusive scan of blocksums[0..nb) in place (nb <= 1024)
__global__ __launch_bounds__(1024)
void scan_blocksums_kernel(int* __restrict__ blocksums, int nb) {
    __shared__ int ts[1024];
    int t = threadIdx.x;
    ts[t] = (t < nb) ? blocksums[t] : 0;
    __syncthreads();
    for (int off = 1; off < 1024; off <<= 1) {
        int u = (t >= off) ? ts[t - off] : 0;
        __syncthreads();
        ts[t] += u;
        __syncthreads();
    }
    if (t < nb) blocksums[t] = (t == 0) ? 0 : ts[t - 1];
}

// offsets = partial + blockbase; also emit bucket cursors at RPB boundaries
__global__ __launch_bounds__(256)
void add_base_kernel(int* __restrict__ offsets,
                     int* __restrict__ bcursor,
                     const int* __restrict__ blocksums, int n) {
    int bb = blocksums[blockIdx.x];
    int base = blockIdx.x * TILE + threadIdx.x * 4;
    if (base + 3 < n) {
        int4 v = *reinterpret_cast<const int4*>(offsets + base);
        v.x += bb; v.y += bb; v.z += bb; v.w += bb;
        *reinterpret_cast<int4*>(offsets + base) = v;
        if ((base & (RPB - 1)) == 0) bcursor[base >> 7] = v.x;  // RPB=128
    } else {
        for (int k = 0; k < 4; ++k) {
            if (base + k < n) {
                int v = offsets[base + k] + bb;
                offsets[base + k] = v;
                if (((base + k) & (RPB - 1)) == 0) bcursor[(base + k) >> 7] = v;
            }
        }
    }
}

// Phase A: bin edges into RPB-row buckets, LDS-staged so global writes are
// runs of consecutive slots. epackA entry: ((localrow<<17)|col, valbits)
__global__ __launch_bounds__(256)
void bin_kernel(const int* __restrict__ row, const int* __restrict__ col,
                const float* __restrict__ vals, int* __restrict__ bcursor,
                int2* __restrict__ epackA, int n_edges, int nb) {
    __shared__ int hist[NBMAX];
    __shared__ int lbase[NBMAX];
    __shared__ int gbase[NBMAX];
    __shared__ int lcur[NBMAX];
    __shared__ int ts[256];
    __shared__ int2 stage[ACHUNK];
    __shared__ int gpos[ACHUNK];
    int t = threadIdx.x;
    int base = blockIdx.x * ACHUNK;
    int m = n_edges - base;
    if (m > ACHUNK) m = ACHUNK;
    for (int i = t; i < nb; i += 256) hist[i] = 0;
    __syncthreads();
    for (int i = t; i < m; i += 256)
        atomicAdd(&hist[row[base + i] >> 7], 1);           // RPB=128
    __syncthreads();
    // exclusive scan hist[0..nb) -> lbase (4 per thread + Hillis-Steele)
    int tb = t * 4;
    int h0 = (tb + 0 < nb) ? hist[tb + 0] : 0;
    int h1 = (tb + 1 < nb) ? hist[tb + 1] : 0;
    int h2 = (tb + 2 < nb) ? hist[tb + 2] : 0;
    int h3 = (tb + 3 < nb) ? hist[tb + 3] : 0;
    int s0 = h0, s1 = s0 + h1, s2 = s1 + h2, s3 = s2 + h3;
    ts[t] = s3;
    __syncthreads();
    for (int off = 1; off < 256; off <<= 1) {
        int u = (t >= off) ? ts[t - off] : 0;
        __syncthreads();
        ts[t] += u;
        __syncthreads();
    }
    int ex = (t == 0) ? 0 : ts[t - 1];
    if (tb + 0 < nb) lbase[tb + 0] = ex;
    if (tb + 1 < nb) lbase[tb + 1] = ex + s0;
    if (tb + 2 < nb) lbase[tb + 2] = ex + s1;
    if (tb + 3 < nb) lbase[tb + 3] = ex + s2;
    __syncthreads();
    // reserve global slices, reset local cursors
    for (int i = t; i < nb; i += 256) {
        gbase[i] = atomicAdd(&bcursor[i], hist[i]);
        lcur[i] = 0;
    }
    __syncthreads();
    // scatter into LDS staging (bucket-major), remember global slot
    for (int i = t; i < m; i += 256) {
        int r = row[base + i];
        int c = col[base + i];
        float v = vals[base + i];
        int bk = r >> 7;                                   // RPB=128
        int lp = atomicAdd(&lcur[bk], 1);
        int sp = lbase[bk] + lp;
        stage[sp] = make_int2(((r & (RPB - 1)) << 17) | c, __float_as_int(v));
        gpos[sp] = gbase[bk] + lp;
    }
    __syncthreads();
    // stream out: consecutive i within a bucket -> consecutive gpos
    for (int i = t; i < m; i += 256)
        epackA[gpos[i]] = stage[i];
}

// Phase B: one block per bucket. Load bucket region, scatter to CSR order via
// LDS row cursors, stream out coalesced to epackB.
__global__ __launch_bounds__(256)
void bucket_sort_kernel(const int* __restrict__ offsets,
                        const int2* __restrict__ epackA,
                        int2* __restrict__ epackB,
                        int n_nodes, int n_edges) {
    __shared__ int2 ein[BCAP];
    __shared__ int2 eout[BCAP];
    __shared__ int rowcur[RPB];
    int b = blockIdx.x;
    int t = threadIdx.x;
    int r0 = b * RPB;
    int begin = offsets[r0];
    int rend = r0 + RPB;
    int end = (rend < n_nodes) ? offsets[rend] : n_edges;
    int n = end - begin;
    if (t < RPB) {
        int rr = r0 + t;
        rowcur[t] = (rr < n_nodes) ? (offsets[rr] - begin) : 0;
    }
    __syncthreads();
    if (n <= BCAP) {
        for (int i = t; i < n; i += 256) ein[i] = epackA[begin + i];
        __syncthreads();
        for (int i = t; i < n; i += 256) {
            int2 e = ein[i];
            int lr = e.x >> 17;
            int pos = atomicAdd(&rowcur[lr], 1);
            eout[pos] = make_int2(e.x & 0x1FFFF, e.y);
        }
        __syncthreads();
        for (int i = t; i < n; i += 256) epackB[begin + i] = eout[i];
    } else {
        // fallback (can't occur for uniform input): chunked scatter to epackB
        for (int cbase = 0; cbase < n; cbase += BCAP) {
            int cm = n - cbase; if (cm > BCAP) cm = BCAP;
            for (int i = t; i < cm; i += 256) ein[i] = epackA[begin + cbase + i];
            __syncthreads();
            for (int i = t; i < cm; i += 256) {
                int2 e = ein[i];
                int lr = e.x >> 17;
                int pos = atomicAdd(&rowcur[lr], 1);
                epackB[begin + pos] = make_int2(e.x & 0x1FFFF, e.y);
            }
            __syncthreads();
        }
    }
}

// one 64-lane wave per destination row; lane owns 2 columns (float2).
// Edge metadata loaded lane-parallel, broadcast via __shfl, gathers 4-wide.
__global__ __launch_bounds__(256)
void csr_gather_kernel(const float* __restrict__ x,
                       const float* __restrict__ x0,
                       const float* __restrict__ alpha,
                       const int* __restrict__ offsets,
                       const int2* __restrict__ epack,
                       float* __restrict__ out, int n_nodes, int n_edges) {
    int gid = blockIdx.x * blockDim.x + threadIdx.x;
    int r = gid >> 6;           // wave (64 lanes) per row
    int lane = gid & 63;        // lane owns float2 -> 128 floats/row
    if (r >= n_nodes) return;
    float s = 0.5f * sigmoidf_(alpha[r]);
    const float2* xp = reinterpret_cast<const float2*>(x);
    int rb = r * 64;            // float2 index of row base
    float2 xv = xp[rb + lane];
    float2 acc = reinterpret_cast<const float2*>(x0)[rb + lane];
    acc.x -= s * xv.x;
    acc.y -= s * xv.y;
    int beg = offsets[r];
    int stop = (r + 1 < n_nodes) ? offsets[r + 1] : n_edges;
    for (int chunk = beg; chunk < stop; chunk += 64) {
        int m = stop - chunk;
        if (m > 64) m = 64;
        int2 e = make_int2(0, 0);
        if (lane < m) e = epack[chunk + lane];
        int k = 0;
        for (; k + 4 <= m; k += 4) {
            int c0 = __shfl(e.x, k + 0);
            int c1 = __shfl(e.x, k + 1);
            int c2 = __shfl(e.x, k + 2);
            int c3 = __shfl(e.x, k + 3);
            float w0 = s * __int_as_float(__shfl(e.y, k + 0));
            float w1 = s * __int_as_float(__shfl(e.y, k + 1));
            float w2 = s * __int_as_float(__shfl(e.y, k + 2));
            float w3 = s * __int_as_float(__shfl(e.y, k + 3));
            float2 v0 = xp[(size_t)c0 * 64 + lane];
            float2 v1 = xp[(size_t)c1 * 64 + lane];
            float2 v2 = xp[(size_t)c2 * 64 + lane];
            float2 v3 = xp[(size_t)c3 * 64 + lane];
            acc.x += w0 * v0.x; acc.y += w0 * v0.y;
            acc.x += w1 * v1.x; acc.y += w1 * v1.y;
            acc.x += w2 * v2.x; acc.y += w2 * v2.y;
            acc.x += w3 * v3.x; acc.y += w3 * v3.y;
        }
        for (; k < m; ++k) {
            int c = __shfl(e.x, k);
            float w = s * __int_as_float(__shfl(e.y, k));
            float2 v = xp[(size_t)c * 64 + lane];
            acc.x += w * v.x;
            acc.y += w * v.y;
        }
    }
    reinterpret_cast<float2*>(out)[rb + lane] = acc;
}

extern "C" void kernel_launch(void* const* d_in, const int* in_sizes, int n_in,
                              void* d_out, int out_size, void* d_ws, size_t ws_size,
                              hipStream_t stream) {
    // inputs: 0=t(unused), 1=x[N,D], 2=x0[N,D], 3=alpha[N], 4=vals[E],
    //         5=row[E](i32), 6=col[E](i32)
    const float* x     = (const float*)d_in[1];
    const float* x0    = (const float*)d_in[2];
    const float* alpha = (const float*)d_in[3];
    const float* vals  = (const float*)d_in[4];
    const int*   row   = (const int*)d_in[5];
    const int*   col   = (const int*)d_in[6];
    float* out = (float*)d_out;

    int n_nodes = in_sizes[3];
    int n_edges = in_sizes[4];
    int nblocks = (n_nodes + TILE - 1) / TILE;     // scan blocks
    int nb = (n_nodes + RPB - 1) / RPB;            // buckets (782)

    // workspace layout
    size_t npad = (size_t)((n_nodes + 3) & ~3);
    int*  counts    = (int*)d_ws;
    int*  offsets   = counts + npad;
    int*  blocksums = offsets + npad;              // 1024
    int*  bcursor   = blocksums + 1024;            // nb (<=1024) padded
    int2* epackA    = (int2*)(bcursor + NBMAX);
    int2* epackB    = epackA + ((n_edges + 3) & ~3);
    // total ~= 2*400KB + 8KB + 2*12.8MB ~= 26.5 MB

    hipMemsetAsync(counts, 0, npad * sizeof(int), stream);

    {
        int block = 256;
        int grid = ((n_edges >> 2) + block - 1) / block;
        if (grid > 4096) grid = 4096;
        hist_kernel<<<grid, block, 0, stream>>>(row, counts, n_edges);
    }
    scan_partial_kernel<<<nblocks, 256, 0, stream>>>(counts, offsets,
                                                     blocksums, n_nodes);
    scan_blocksums_kernel<<<1, 1024, 0, stream>>>(blocksums, nblocks);
    add_base_kernel<<<nblocks, 256, 0, stream>>>(offsets, bcursor, blocksums,
                                                 n_nodes);
    {
        int grid = (n_edges + ACHUNK - 1) / ACHUNK;
        bin_kernel<<<grid, 256, 0, stream>>>(row, col, vals, bcursor, epackA,
                                             n_edges, nb);
    }
    bucket_sort_kernel<<<nb, 256, 0, stream>>>(offsets, epackA, epackB,
                                               n_nodes, n_edges);
    {
        long long total = (long long)n_nodes * 64;
        int block = 256;
        int grid = (int)((total + block - 1) / block);
        csr_gather_kernel<<<grid, block, 0, stream>>>(x, x0, alpha, offsets,
                                                      epackB, out, n_nodes,
                                                      n_edges);
    }
}